// Round 4
// baseline (148.800 us; speedup 1.0000x reference)
//
#include <hip/hip_runtime.h>

#define NB   4
#define NPTS 1024
#define HID  64

typedef float f32x4 __attribute__((ext_vector_type(4)));
typedef float f32x2 __attribute__((ext_vector_type(2)));
typedef short bf16x8 __attribute__((ext_vector_type(8)));
typedef unsigned int u32;
typedef unsigned short u16;

// f32 -> bf16 RTNE (scalar, for precompute)
__device__ inline u16 f2bf(float x) {
    union { float f; unsigned u; } v; v.f = x;
    return (u16)((v.u + 0x7FFFu + ((v.u >> 16) & 1u)) >> 16);
}
// HW packed f32->bf16 (RTNE), one VALU op
__device__ inline u32 cvt_pk_bf16(float lo, float hi) {
    u32 r; asm("v_cvt_pk_bf16_f32 %0, %1, %2" : "=v"(r) : "v"(lo), "v"(hi)); return r;
}
// packed relu on 2x bf16: bf16 ordering is monotone under signed-i16 compare
// (negatives incl. -0 have sign bit -> i16 < 0 -> clamped to +0)
__device__ inline u32 pk_relu2(u32 a) {
    u32 r; asm("v_pk_max_i16 %0, %1, 0" : "=v"(r) : "v"(a)); return r;
}

// Block 0..1023: P[b][n][k] = concat(pos,vel)[b][n][:] . W1[:][k]
// Block 1024:    W2T_bf16[ch][k] = bf16(W2[k][ch])   (8 KB, L2-resident)
__global__ __launch_bounds__(256) void precompute(
    const float* __restrict__ pos, const float* __restrict__ vel,
    const float* __restrict__ W1, const float* __restrict__ W2,
    float* __restrict__ P, u16* __restrict__ W2T) {
    if (blockIdx.x == NB * NPTS / 4) {
        for (int e = threadIdx.x; e < HID * HID; e += 256) {
            const int ch = e >> 6, k = e & 63;
            W2T[e] = f2bf(W2[k * HID + ch]);
        }
        return;
    }
    const int t   = blockIdx.x * 256 + threadIdx.x;
    const int row = t >> 6;          // b*NPTS + n
    const int k   = t & 63;
    const float* pp = pos + row * 3;
    const float* vv = vel + row * 3;
    float acc = 0.f;
    #pragma unroll
    for (int c = 0; c < 3; ++c) acc = fmaf(pp[c], W1[c * HID + k], acc);
    #pragma unroll
    for (int c = 0; c < 3; ++c) acc = fmaf(vv[c], W1[(3 + c) * HID + k], acc);
    P[row * HID + k] = acc;
}

__global__ __launch_bounds__(256) void inet_mfma(
    const float* __restrict__ P,  const float* __restrict__ b1,
    const u16* __restrict__ W2T,  const float* __restrict__ b2,
    const float* __restrict__ W3, float* __restrict__ out) {
    __shared__ float sH[4][HID];

    const int tid  = threadIdx.x;
    const int wv   = tid >> 6;
    const int lane = tid & 63;
    const int c    = lane & 15;   // edge-col / channel-col within 16
    const int g    = lane >> 4;   // k-group

    const int b = blockIdx.x >> 10;
    const int i = blockIdx.x & (NPTS - 1);

    // Per-lane k slots: pair d (0..7) covers k = (d>>2)*32 + g*8 + (d&3)*2 (+1)
    const float* Pi = P + ((size_t)(b * NPTS + i)) * HID;
    f32x2 qp2[8], qm2[8];                 // b1 -/+ P[i], packed pairs
    #pragma unroll
    for (int d = 0; d < 8; ++d) {
        const int k = (d >> 2) * 32 + g * 8 + (d & 3) * 2;
        f32x2 bb = *(const f32x2*)(b1 + k);
        f32x2 pp = *(const f32x2*)(Pi + k);
        qp2[d] = bb - pp;
        qm2[d] = bb + pp;
    }

    // B fragments straight from pre-transposed bf16 weights (16B coalesced, L2)
    bf16x8 Bf[8];
    #pragma unroll
    for (int kk = 0; kk < 2; ++kk)
        #pragma unroll
        for (int n = 0; n < 4; ++n)
            Bf[kk * 4 + n] = *(const bf16x8*)(W2T + (n * 16 + c) * HID + kk * 32 + g * 8);

    // loop-invariant MFMA C-initializer carrying the b2 bias (no per-tile movs)
    f32x4 Cinit[4];
    #pragma unroll
    for (int n = 0; n < 4; ++n) {
        const float bv = b2[n * 16 + c];
        Cinit[n] = (f32x4){bv, bv, bv, bv};
    }

    f32x2 H[4][2];
    #pragma unroll
    for (int n = 0; n < 4; ++n) { H[n][0] = (f32x2){0.f, 0.f}; H[n][1] = (f32x2){0.f, 0.f}; }

    const float* pj_ptr = P + ((size_t)b * NPTS) * HID + (wv * 16 + c) * HID;

    for (int t = wv; t < NPTS / 16; t += 4, pj_ptr += 4 * 16 * HID) {
        f32x2 pj2[8];
        #pragma unroll
        for (int kk = 0; kk < 2; ++kk) {
            const int k0 = kk * 32 + g * 8;
            f32x4 v0 = *(const f32x4*)(pj_ptr + k0);
            f32x4 v1 = *(const f32x4*)(pj_ptr + k0 + 4);
            pj2[kk * 4 + 0] = (f32x2){v0.x, v0.y};
            pj2[kk * 4 + 1] = (f32x2){v0.z, v0.w};
            pj2[kk * 4 + 2] = (f32x2){v1.x, v1.y};
            pj2[kk * 4 + 3] = (f32x2){v1.z, v1.w};
        }

        // A fragments, both signs:  +: relu(pj + qp)   -: relu(qm - pj)
        union { bf16x8 v; u32 u[4]; } ap[2], am[2];
        #pragma unroll
        for (int kk = 0; kk < 2; ++kk)
            #pragma unroll
            for (int d = 0; d < 4; ++d) {
                f32x2 tp = pj2[kk * 4 + d] + qp2[kk * 4 + d];   // v_pk_add_f32
                f32x2 tm = qm2[kk * 4 + d] - pj2[kk * 4 + d];   // v_pk_add_f32(neg)
                ap[kk].u[d] = pk_relu2(cvt_pk_bf16(tp.x, tp.y));
                am[kk].u[d] = pk_relu2(cvt_pk_bf16(tm.x, tm.y));
            }

        #pragma unroll
        for (int n = 0; n < 4; ++n) {
            f32x4 Cp = __builtin_amdgcn_mfma_f32_16x16x32_bf16(ap[0].v, Bf[n],     Cinit[n], 0, 0, 0);
            Cp       = __builtin_amdgcn_mfma_f32_16x16x32_bf16(ap[1].v, Bf[4 + n], Cp,       0, 0, 0);
            f32x4 Cm = __builtin_amdgcn_mfma_f32_16x16x32_bf16(am[0].v, Bf[n],     Cinit[n], 0, 0, 0);
            Cm       = __builtin_amdgcn_mfma_f32_16x16x32_bf16(am[1].v, Bf[4 + n], Cm,       0, 0, 0);
            f32x2 p01 = {fmaxf(Cp[0], 0.f), fmaxf(Cp[1], 0.f)};
            f32x2 p23 = {fmaxf(Cp[2], 0.f), fmaxf(Cp[3], 0.f)};
            f32x2 m01 = {fmaxf(Cm[0], 0.f), fmaxf(Cm[1], 0.f)};
            f32x2 m23 = {fmaxf(Cm[2], 0.f), fmaxf(Cm[3], 0.f)};
            H[n][0] += p01 - m01;                               // v_pk_add_f32 x2
            H[n][1] += p23 - m23;
        }
    }

    // Reduce: per-lane sum over its 4 edge-rows, then over g-groups
    float s[4];
    #pragma unroll
    for (int n = 0; n < 4; ++n) {
        f32x2 hv = H[n][0] + H[n][1];
        float v = hv.x + hv.y;
        v += __shfl_xor(v, 16, 64);
        v += __shfl_xor(v, 32, 64);
        s[n] = v;
    }
    if (lane < 16) {
        #pragma unroll
        for (int n = 0; n < 4; ++n) sH[wv][n * 16 + lane] = s[n];
    }
    __syncthreads();

    if (tid < HID) {
        const int col = tid;
        const float Hs = sH[0][col] + sH[1][col] + sH[2][col] + sH[3][col];
        float f0 = Hs * W3[col * 3 + 0];
        float f1 = Hs * W3[col * 3 + 1];
        float f2 = Hs * W3[col * 3 + 2];
        #pragma unroll
        for (int off = 32; off; off >>= 1) {
            f0 += __shfl_xor(f0, off, 64);
            f1 += __shfl_xor(f1, off, 64);
            f2 += __shfl_xor(f2, off, 64);
        }
        if (tid == 0) {
            out[(b * NPTS + i) * 3 + 0] = 0.5f * f0;
            out[(b * NPTS + i) * 3 + 1] = 0.5f * f1;
            out[(b * NPTS + i) * 3 + 2] = 0.5f * f2;
        }
    }
}

extern "C" void kernel_launch(void* const* d_in, const int* in_sizes, int n_in,
                              void* d_out, int out_size, void* d_ws, size_t ws_size,
                              hipStream_t stream) {
    const float* pos = (const float*)d_in[0];
    const float* vel = (const float*)d_in[1];
    const float* W1  = (const float*)d_in[2];
    const float* b1  = (const float*)d_in[3];
    const float* W2  = (const float*)d_in[4];
    const float* b2  = (const float*)d_in[5];
    const float* W3  = (const float*)d_in[6];
    const float* b3  = (const float*)d_in[7];   // cancels in antisymmetrization
    (void)b3;
    float* out = (float*)d_out;
    float* P   = (float*)d_ws;                            // 1 MB
    u16*   W2T = (u16*)((char*)d_ws + (size_t)NB * NPTS * HID * 4);  // 8 KB

    precompute<<<dim3(NB * NPTS / 4 + 1), dim3(256), 0, stream>>>(pos, vel, W1, W2, P, W2T);
    inet_mfma<<<dim3(NB * NPTS), dim3(256), 0, stream>>>(P, b1, W2T, b2, W3, out);
}

// Round 5
// 148.108 us; speedup vs baseline: 1.0047x; 1.0047x over previous
//
#include <hip/hip_runtime.h>

#define NB   4
#define NPTS 1024
#define HID  64

typedef float f32x4 __attribute__((ext_vector_type(4)));
typedef float f32x2 __attribute__((ext_vector_type(2)));
typedef short bf16x8 __attribute__((ext_vector_type(8)));
typedef unsigned int u32;
typedef unsigned short u16;

// f32 -> bf16 RTNE (scalar, for precompute)
__device__ inline u16 f2bf(float x) {
    union { float f; unsigned u; } v; v.f = x;
    return (u16)((v.u + 0x7FFFu + ((v.u >> 16) & 1u)) >> 16);
}
// HW packed f32->bf16 (RTNE), one VALU op
__device__ inline u32 cvt_pk_bf16(float lo, float hi) {
    u32 r; asm("v_cvt_pk_bf16_f32 %0, %1, %2" : "=v"(r) : "v"(lo), "v"(hi)); return r;
}
// packed relu on 2x bf16 (bf16 order is monotone under signed-i16 compare)
__device__ inline u32 pk_relu2(u32 a) {
    u32 r; asm("v_pk_max_i16 %0, %1, 0" : "=v"(r) : "v"(a)); return r;
}

// Blocks 0..1023: P[b][n][k] = concat(pos,vel)[b][n][:] . W1[:][k]
// Block 1024:     W2T_bf16[ch][k] = bf16(W2[k][ch])   (8 KB, L2-resident)
__global__ __launch_bounds__(256) void precompute(
    const float* __restrict__ pos, const float* __restrict__ vel,
    const float* __restrict__ W1, const float* __restrict__ W2,
    float* __restrict__ P, u16* __restrict__ W2T) {
    if (blockIdx.x == NB * NPTS / 4) {
        for (int e = threadIdx.x; e < HID * HID; e += 256) {
            const int ch = e >> 6, k = e & 63;
            W2T[e] = f2bf(W2[k * HID + ch]);
        }
        return;
    }
    const int t   = blockIdx.x * 256 + threadIdx.x;
    const int row = t >> 6;          // b*NPTS + n
    const int k   = t & 63;
    const float* pp = pos + row * 3;
    const float* vv = vel + row * 3;
    float acc = 0.f;
    #pragma unroll
    for (int c = 0; c < 3; ++c) acc = fmaf(pp[c], W1[c * HID + k], acc);
    #pragma unroll
    for (int c = 0; c < 3; ++c) acc = fmaf(vv[c], W1[(3 + c) * HID + k], acc);
    P[row * HID + k] = acc;
}

__global__ __launch_bounds__(256) void inet_mfma(
    const float* __restrict__ P,  const float* __restrict__ b1,
    const u16* __restrict__ W2T,  const float* __restrict__ b2,
    const float* __restrict__ W3, float* __restrict__ out) {
    __shared__ float sH[4][HID];

    const int tid  = threadIdx.x;
    const int wv   = tid >> 6;
    const int lane = tid & 63;
    const int c    = lane & 15;   // edge-col / channel-col within 16
    const int g    = lane >> 4;   // k-group

    const int b = blockIdx.x >> 10;
    const int i = blockIdx.x & (NPTS - 1);

    // Per-lane k slots: pair d (0..7) covers k = (d>>2)*32 + g*8 + (d&3)*2 (+1)
    const float* Pi = P + ((size_t)(b * NPTS + i)) * HID;
    f32x2 qp2[8], qm2[8];                 // b1 -/+ P[i], packed pairs
    #pragma unroll
    for (int d = 0; d < 8; ++d) {
        const int k = (d >> 2) * 32 + g * 8 + (d & 3) * 2;
        f32x2 bb = *(const f32x2*)(b1 + k);
        f32x2 pp = *(const f32x2*)(Pi + k);
        qp2[d] = bb - pp;
        qm2[d] = bb + pp;
    }

    // B fragments straight from pre-transposed bf16 weights (16B coalesced, L2)
    bf16x8 Bf[8];
    #pragma unroll
    for (int kk = 0; kk < 2; ++kk)
        #pragma unroll
        for (int n = 0; n < 4; ++n)
            Bf[kk * 4 + n] = *(const bf16x8*)(W2T + (n * 16 + c) * HID + kk * 32 + g * 8);

    // loop-invariant MFMA C-initializer carrying the b2 bias
    f32x4 Cinit[4];
    #pragma unroll
    for (int n = 0; n < 4; ++n) {
        const float bv = b2[n * 16 + c];
        Cinit[n] = (f32x4){bv, bv, bv, bv};
    }

    f32x2 H[4][2];
    #pragma unroll
    for (int n = 0; n < 4; ++n) { H[n][0] = (f32x2){0.f, 0.f}; H[n][1] = (f32x2){0.f, 0.f}; }

    const float* Pb = P + ((size_t)b * NPTS) * HID;
    const int koff = g * 8;

    // ---- 1-deep software pipeline: prefetch tile t+4 while computing t ----
    f32x4 nv0, nv1, nv2, nv3;
    {
        const float* base = Pb + (size_t)(wv * 16 + c) * HID;
        nv0 = *(const f32x4*)(base + koff);
        nv1 = *(const f32x4*)(base + koff + 4);
        nv2 = *(const f32x4*)(base + 32 + koff);
        nv3 = *(const f32x4*)(base + 32 + koff + 4);
    }

    for (int t = wv; t < NPTS / 16; t += 4) {
        const f32x4 c0 = nv0, c1 = nv1, c2 = nv2, c3 = nv3;

        const int tn = (t + 4 < NPTS / 16) ? (t + 4) : t;   // clamp: reload own tile on last iter
        const float* base = Pb + (size_t)(tn * 16 + c) * HID;
        nv0 = *(const f32x4*)(base + koff);
        nv1 = *(const f32x4*)(base + koff + 4);
        nv2 = *(const f32x4*)(base + 32 + koff);
        nv3 = *(const f32x4*)(base + 32 + koff + 4);

        f32x2 pj2[8];
        pj2[0] = (f32x2){c0.x, c0.y};  pj2[1] = (f32x2){c0.z, c0.w};
        pj2[2] = (f32x2){c1.x, c1.y};  pj2[3] = (f32x2){c1.z, c1.w};
        pj2[4] = (f32x2){c2.x, c2.y};  pj2[5] = (f32x2){c2.z, c2.w};
        pj2[6] = (f32x2){c3.x, c3.y};  pj2[7] = (f32x2){c3.z, c3.w};

        // A fragments, both signs:  +: relu(pj + qp)   -: relu(qm - pj)
        union { bf16x8 v; u32 u[4]; } ap[2], am[2];
        #pragma unroll
        for (int kk = 0; kk < 2; ++kk)
            #pragma unroll
            for (int d = 0; d < 4; ++d) {
                f32x2 tp = pj2[kk * 4 + d] + qp2[kk * 4 + d];   // v_pk_add_f32
                f32x2 tm = qm2[kk * 4 + d] - pj2[kk * 4 + d];
                ap[kk].u[d] = pk_relu2(cvt_pk_bf16(tp.x, tp.y));
                am[kk].u[d] = pk_relu2(cvt_pk_bf16(tm.x, tm.y));
            }

        #pragma unroll
        for (int n = 0; n < 4; ++n) {
            f32x4 Cp = __builtin_amdgcn_mfma_f32_16x16x32_bf16(ap[0].v, Bf[n],     Cinit[n], 0, 0, 0);
            Cp       = __builtin_amdgcn_mfma_f32_16x16x32_bf16(ap[1].v, Bf[4 + n], Cp,       0, 0, 0);
            f32x4 Cm = __builtin_amdgcn_mfma_f32_16x16x32_bf16(am[0].v, Bf[n],     Cinit[n], 0, 0, 0);
            Cm       = __builtin_amdgcn_mfma_f32_16x16x32_bf16(am[1].v, Bf[4 + n], Cm,       0, 0, 0);
            f32x2 p01 = {fmaxf(Cp[0], 0.f), fmaxf(Cp[1], 0.f)};
            f32x2 p23 = {fmaxf(Cp[2], 0.f), fmaxf(Cp[3], 0.f)};
            f32x2 m01 = {fmaxf(Cm[0], 0.f), fmaxf(Cm[1], 0.f)};
            f32x2 m23 = {fmaxf(Cm[2], 0.f), fmaxf(Cm[3], 0.f)};
            H[n][0] += p01 - m01;
            H[n][1] += p23 - m23;
        }
    }

    // Reduce: per-lane sum over its 4 edge-rows, then over g-groups
    float s[4];
    #pragma unroll
    for (int n = 0; n < 4; ++n) {
        f32x2 hv = H[n][0] + H[n][1];
        float v = hv.x + hv.y;
        v += __shfl_xor(v, 16, 64);
        v += __shfl_xor(v, 32, 64);
        s[n] = v;
    }
    if (lane < 16) {
        #pragma unroll
        for (int n = 0; n < 4; ++n) sH[wv][n * 16 + lane] = s[n];
    }
    __syncthreads();

    if (tid < HID) {
        const int col = tid;
        const float Hs = sH[0][col] + sH[1][col] + sH[2][col] + sH[3][col];
        float f0 = Hs * W3[col * 3 + 0];
        float f1 = Hs * W3[col * 3 + 1];
        float f2 = Hs * W3[col * 3 + 2];
        #pragma unroll
        for (int off = 32; off; off >>= 1) {
            f0 += __shfl_xor(f0, off, 64);
            f1 += __shfl_xor(f1, off, 64);
            f2 += __shfl_xor(f2, off, 64);
        }
        if (tid == 0) {
            out[(b * NPTS + i) * 3 + 0] = 0.5f * f0;
            out[(b * NPTS + i) * 3 + 1] = 0.5f * f1;
            out[(b * NPTS + i) * 3 + 2] = 0.5f * f2;
        }
    }
}

extern "C" void kernel_launch(void* const* d_in, const int* in_sizes, int n_in,
                              void* d_out, int out_size, void* d_ws, size_t ws_size,
                              hipStream_t stream) {
    const float* pos = (const float*)d_in[0];
    const float* vel = (const float*)d_in[1];
    const float* W1  = (const float*)d_in[2];
    const float* b1  = (const float*)d_in[3];
    const float* W2  = (const float*)d_in[4];
    const float* b2  = (const float*)d_in[5];
    const float* W3  = (const float*)d_in[6];
    const float* b3  = (const float*)d_in[7];   // cancels in antisymmetrization
    (void)b3;
    float* out = (float*)d_out;
    float* P   = (float*)d_ws;                                        // 1 MB
    u16*   W2T = (u16*)((char*)d_ws + (size_t)NB * NPTS * HID * 4);   // 8 KB

    precompute<<<dim3(NB * NPTS / 4 + 1), dim3(256), 0, stream>>>(pos, vel, W1, W2, P, W2T);
    inet_mfma<<<dim3(NB * NPTS), dim3(256), 0, stream>>>(P, b1, W2T, b2, W3, out);
}

// Round 6
// 133.863 us; speedup vs baseline: 1.1116x; 1.1064x over previous
//
#include <hip/hip_runtime.h>

#define NB   4
#define NPTS 1024
#define HID  64

typedef float f32x4 __attribute__((ext_vector_type(4)));
typedef float f32x2 __attribute__((ext_vector_type(2)));
typedef short bf16x8 __attribute__((ext_vector_type(8)));
typedef unsigned int u32;
typedef unsigned short u16;

// f32 -> bf16 RTNE (scalar, for precompute)
__device__ inline u16 f2bf(float x) {
    union { float f; unsigned u; } v; v.f = x;
    return (u16)((v.u + 0x7FFFu + ((v.u >> 16) & 1u)) >> 16);
}
// HW packed f32->bf16 (RTNE), one VALU op
__device__ inline u32 cvt_pk_bf16(float lo, float hi) {
    u32 r; asm("v_cvt_pk_bf16_f32 %0, %1, %2" : "=v"(r) : "v"(lo), "v"(hi)); return r;
}
// packed relu on 2x bf16 (bf16 order is monotone under signed-i16 compare)
__device__ inline u32 pk_relu2(u32 a) {
    u32 r; asm("v_pk_max_i16 %0, %1, 0" : "=v"(r) : "v"(a)); return r;
}

// Blocks 0..1023: P[b][n][k] = concat(pos,vel)[b][n][:] . W1[:][k]
// Block 1024:     W2T_bf16[ch][k] = bf16(W2[k][ch])   (8 KB, L2-resident)
__global__ __launch_bounds__(256) void precompute(
    const float* __restrict__ pos, const float* __restrict__ vel,
    const float* __restrict__ W1, const float* __restrict__ W2,
    float* __restrict__ P, u16* __restrict__ W2T) {
    if (blockIdx.x == NB * NPTS / 4) {
        for (int e = threadIdx.x; e < HID * HID; e += 256) {
            const int ch = e >> 6, k = e & 63;
            W2T[e] = f2bf(W2[k * HID + ch]);
        }
        return;
    }
    const int t   = blockIdx.x * 256 + threadIdx.x;
    const int row = t >> 6;          // b*NPTS + n
    const int k   = t & 63;
    const float* pp = pos + row * 3;
    const float* vv = vel + row * 3;
    float acc = 0.f;
    #pragma unroll
    for (int c = 0; c < 3; ++c) acc = fmaf(pp[c], W1[c * HID + k], acc);
    #pragma unroll
    for (int c = 0; c < 3; ++c) acc = fmaf(vv[c], W1[(3 + c) * HID + k], acc);
    P[row * HID + k] = acc;
}

// One 64-thread block (one wave) per output row i. No LDS, no syncthreads.
__global__ __launch_bounds__(64, 4) void inet_mfma(
    const float* __restrict__ P,  const float* __restrict__ b1,
    const u16* __restrict__ W2T,  const float* __restrict__ b2,
    const float* __restrict__ W3, float* __restrict__ out) {
    const int lane = threadIdx.x;   // 0..63
    const int c    = lane & 15;     // edge-col / channel-col within 16
    const int g    = lane >> 4;     // k-group

    const int b = blockIdx.x >> 10;
    const int i = blockIdx.x & (NPTS - 1);

    // Per-lane k slots: pair d (0..7) covers k = (d>>2)*32 + g*8 + (d&3)*2 (+1)
    const float* Pi = P + ((size_t)(b * NPTS + i)) * HID;
    f32x2 qp2[8], qm2[8];                 // b1 -/+ P[i], packed pairs
    #pragma unroll
    for (int d = 0; d < 8; ++d) {
        const int k = (d >> 2) * 32 + g * 8 + (d & 3) * 2;
        f32x2 bb = *(const f32x2*)(b1 + k);
        f32x2 pp = *(const f32x2*)(Pi + k);
        qp2[d] = bb - pp;
        qm2[d] = bb + pp;
    }

    // B fragments from pre-transposed bf16 weights (16B coalesced, L2-resident)
    bf16x8 Bf[8];
    #pragma unroll
    for (int kk = 0; kk < 2; ++kk)
        #pragma unroll
        for (int n = 0; n < 4; ++n)
            Bf[kk * 4 + n] = *(const bf16x8*)(W2T + (n * 16 + c) * HID + kk * 32 + g * 8);

    float b2v[4];
    #pragma unroll
    for (int n = 0; n < 4; ++n) b2v[n] = b2[n * 16 + c];

    f32x2 H[4][2];
    #pragma unroll
    for (int n = 0; n < 4; ++n) { H[n][0] = (f32x2){0.f, 0.f}; H[n][1] = (f32x2){0.f, 0.f}; }

    const float* Pb = P + ((size_t)b * NPTS) * HID;
    const int koff = g * 8;

    // 64 tiles of 16 edges; unroll x2 so two tiles' load->build->MFMA->accum
    // chains interleave inside the wave (ILP latency hiding).
    #pragma unroll 2
    for (int t = 0; t < NPTS / 16; ++t) {
        const float* base = Pb + (size_t)(t * 16 + c) * HID + koff;
        f32x4 v0 = *(const f32x4*)(base);
        f32x4 v1 = *(const f32x4*)(base + 4);
        f32x4 v2 = *(const f32x4*)(base + 32);
        f32x4 v3 = *(const f32x4*)(base + 32 + 4);

        f32x2 pj2[8];
        pj2[0] = (f32x2){v0.x, v0.y};  pj2[1] = (f32x2){v0.z, v0.w};
        pj2[2] = (f32x2){v1.x, v1.y};  pj2[3] = (f32x2){v1.z, v1.w};
        pj2[4] = (f32x2){v2.x, v2.y};  pj2[5] = (f32x2){v2.z, v2.w};
        pj2[6] = (f32x2){v3.x, v3.y};  pj2[7] = (f32x2){v3.z, v3.w};

        // A fragments, both signs:  +: relu(pj + qp)   -: relu(qm - pj)
        union { bf16x8 v; u32 u[4]; } ap[2], am[2];
        #pragma unroll
        for (int kk = 0; kk < 2; ++kk)
            #pragma unroll
            for (int d = 0; d < 4; ++d) {
                f32x2 tp = pj2[kk * 4 + d] + qp2[kk * 4 + d];   // v_pk_add_f32
                f32x2 tm = qm2[kk * 4 + d] - pj2[kk * 4 + d];
                ap[kk].u[d] = pk_relu2(cvt_pk_bf16(tp.x, tp.y));
                am[kk].u[d] = pk_relu2(cvt_pk_bf16(tm.x, tm.y));
            }

        #pragma unroll
        for (int n = 0; n < 4; ++n) {
            const f32x4 Ci = {b2v[n], b2v[n], b2v[n], b2v[n]};
            f32x4 Cp = __builtin_amdgcn_mfma_f32_16x16x32_bf16(ap[0].v, Bf[n],     Ci, 0, 0, 0);
            Cp       = __builtin_amdgcn_mfma_f32_16x16x32_bf16(ap[1].v, Bf[4 + n], Cp, 0, 0, 0);
            f32x4 Cm = __builtin_amdgcn_mfma_f32_16x16x32_bf16(am[0].v, Bf[n],     Ci, 0, 0, 0);
            Cm       = __builtin_amdgcn_mfma_f32_16x16x32_bf16(am[1].v, Bf[4 + n], Cm, 0, 0, 0);
            f32x2 p01 = {fmaxf(Cp[0], 0.f), fmaxf(Cp[1], 0.f)};
            f32x2 p23 = {fmaxf(Cp[2], 0.f), fmaxf(Cp[3], 0.f)};
            f32x2 m01 = {fmaxf(Cm[0], 0.f), fmaxf(Cm[1], 0.f)};
            f32x2 m23 = {fmaxf(Cm[2], 0.f), fmaxf(Cm[3], 0.f)};
            H[n][0] += p01 - m01;
            H[n][1] += p23 - m23;
        }
    }

    // In-wave reduce. C layout: lane holds ch = n*16+c, edge rows g*4+r.
    // Sum r in-register, then g via xor 16/32 (result replicated over g).
    float s[4];
    #pragma unroll
    for (int n = 0; n < 4; ++n) {
        f32x2 hv = H[n][0] + H[n][1];
        float v = hv.x + hv.y;
        v += __shfl_xor(v, 16, 64);
        v += __shfl_xor(v, 32, 64);
        s[n] = v;
    }
    // Apply W3 per channel, then reduce over the 16 c's (replicated over g).
    float f0 = 0.f, f1 = 0.f, f2 = 0.f;
    #pragma unroll
    for (int n = 0; n < 4; ++n) {
        const int ch = n * 16 + c;
        f0 = fmaf(s[n], W3[ch * 3 + 0], f0);
        f1 = fmaf(s[n], W3[ch * 3 + 1], f1);
        f2 = fmaf(s[n], W3[ch * 3 + 2], f2);
    }
    #pragma unroll
    for (int off = 8; off; off >>= 1) {
        f0 += __shfl_xor(f0, off, 64);
        f1 += __shfl_xor(f1, off, 64);
        f2 += __shfl_xor(f2, off, 64);
    }
    if (lane == 0) {
        out[(b * NPTS + i) * 3 + 0] = 0.5f * f0;
        out[(b * NPTS + i) * 3 + 1] = 0.5f * f1;
        out[(b * NPTS + i) * 3 + 2] = 0.5f * f2;
    }
}

extern "C" void kernel_launch(void* const* d_in, const int* in_sizes, int n_in,
                              void* d_out, int out_size, void* d_ws, size_t ws_size,
                              hipStream_t stream) {
    const float* pos = (const float*)d_in[0];
    const float* vel = (const float*)d_in[1];
    const float* W1  = (const float*)d_in[2];
    const float* b1  = (const float*)d_in[3];
    const float* W2  = (const float*)d_in[4];
    const float* b2  = (const float*)d_in[5];
    const float* W3  = (const float*)d_in[6];
    const float* b3  = (const float*)d_in[7];   // cancels in antisymmetrization
    (void)b3;
    float* out = (float*)d_out;
    float* P   = (float*)d_ws;                                        // 1 MB
    u16*   W2T = (u16*)((char*)d_ws + (size_t)NB * NPTS * HID * 4);   // 8 KB

    precompute<<<dim3(NB * NPTS / 4 + 1), dim3(256), 0, stream>>>(pos, vel, W1, W2, P, W2T);
    inet_mfma<<<dim3(NB * NPTS), dim3(64), 0, stream>>>(P, b1, W2T, b2, W3, out);
}